// Round 14
// baseline (580.935 us; speedup 1.0000x reference)
//
#include <hip/hip_runtime.h>
#include <math.h>

#define NROWS   512
#define NSTEPS  256
#define NSLOT   17
#define PKSTEPS (NSTEPS + 2)   // +2 identity pad steps so prefetch overruns safely

// Packet stream [step][slot 0..16][lane 0..63] float4 (~4.5 MB).
// Lane l owns rows 8l..8l+7; even pairs 4l..4l+3; odd pairs 4l..4l+3 (+cB=4l-1).
//  s0,s1   : E(2i)  pairs (t,r) 4l..4l+3
//  s2..s5  : P(2i)  rows (re,im) 8l..8l+7
//  s6,s7   : E(2i+1)
//  s8,s9   : O(2i)  pairs 4l..4l+3 (pair 255 -> identity)
//  s10..s13: P(2i+1)
//  s14,s15 : O(2i+1)
//  s16     : (O0cB.t,.r, O1cB.t,.r)  cB = odd pair 4l-1 (l==0 -> identity)
// Edge pairs carry identity coeffs (1,0) -> unguarded boundary updates are
// exact for rows 0/511 (shfl clamp value is multiplied by r=0).
__device__ float4 g_pk[PKSTEPS * NSLOT * 64];
__device__ float2 g_io[1024];  // [0,512) Pin, [512,1024) Pout

// ---------------- coefficient precompute ----------------

__device__ __forceinline__ float2 pc_coef(float th, float loss) {
  float a = sqrtf(1.0f - loss);
  float s, c;
  sincosf(th, &s, &c);
  return make_float2(a * c, a * s);
}
__device__ __forceinline__ float2 mmi_coef(float loss, float imb) {
  float a = sqrtf(1.0f - loss);
  return make_float2(a * sqrtf(0.5f + imb), a * sqrtf(0.5f - imb));
}

__global__ __launch_bounds__(64) void precomp_kernel(
    const float* __restrict__ thf,  const float* __restrict__ thio,
    const float* __restrict__ lpf,  const float* __restrict__ lpio,
    const float* __restrict__ le,   const float* __restrict__ lo,
    const float* __restrict__ ie,   const float* __restrict__ io2) {
  const int b = blockIdx.x;
  const int l = threadIdx.x;
  if (b >= PKSTEPS) {
    int j = (b - PKSTEPS) * 64 + l;   // 8 blocks -> j in [0,512)
    g_io[j]       = pc_coef(thio[j],       lpio[j]);        // Pin
    g_io[j + 512] = pc_coef(thio[j + 512], lpio[j + 512]);  // Pout
    return;
  }

  float4 F[NSLOT];
  if (b >= NSTEPS) {                  // pad steps: identity everywhere
    #pragma unroll
    for (int s = 0; s < NSLOT; ++s) F[s] = make_float4(1.f, 0.f, 1.f, 0.f);
  } else {
    const int L0 = 2 * b, L1 = 2 * b + 1;
    const int r0 = 8 * l, p0 = 4 * l;
    float2 one = make_float2(1.0f, 0.0f);

    float2 e0[4], e1[4], o0[4], o1[4], q0[8], q1[8];
    #pragma unroll
    for (int j = 0; j < 4; ++j) {
      int p = p0 + j;
      e0[j] = mmi_coef(le[L0 * 256 + p], ie[L0 * 256 + p]);
      e1[j] = mmi_coef(le[L1 * 256 + p], ie[L1 * 256 + p]);
      o0[j] = (p <= 254) ? mmi_coef(lo[L0 * 255 + p], io2[L0 * 255 + p]) : one;
      o1[j] = (p <= 254) ? mmi_coef(lo[L1 * 255 + p], io2[L1 * 255 + p]) : one;
    }
    #pragma unroll
    for (int j = 0; j < 8; ++j) {
      int r = r0 + j;
      q0[j] = pc_coef(thf[L0 * 512 + r], lpf[L0 * 512 + r]);
      q1[j] = pc_coef(thf[L1 * 512 + r], lpf[L1 * 512 + r]);
    }
    float2 b0 = (l > 0) ? mmi_coef(lo[L0 * 255 + p0 - 1], io2[L0 * 255 + p0 - 1]) : one;
    float2 b1 = (l > 0) ? mmi_coef(lo[L1 * 255 + p0 - 1], io2[L1 * 255 + p0 - 1]) : one;

    F[0]  = make_float4(e0[0].x, e0[0].y, e0[1].x, e0[1].y);
    F[1]  = make_float4(e0[2].x, e0[2].y, e0[3].x, e0[3].y);
    F[2]  = make_float4(q0[0].x, q0[0].y, q0[1].x, q0[1].y);
    F[3]  = make_float4(q0[2].x, q0[2].y, q0[3].x, q0[3].y);
    F[4]  = make_float4(q0[4].x, q0[4].y, q0[5].x, q0[5].y);
    F[5]  = make_float4(q0[6].x, q0[6].y, q0[7].x, q0[7].y);
    F[6]  = make_float4(e1[0].x, e1[0].y, e1[1].x, e1[1].y);
    F[7]  = make_float4(e1[2].x, e1[2].y, e1[3].x, e1[3].y);
    F[8]  = make_float4(o0[0].x, o0[0].y, o0[1].x, o0[1].y);
    F[9]  = make_float4(o0[2].x, o0[2].y, o0[3].x, o0[3].y);
    F[10] = make_float4(q1[0].x, q1[0].y, q1[1].x, q1[1].y);
    F[11] = make_float4(q1[2].x, q1[2].y, q1[3].x, q1[3].y);
    F[12] = make_float4(q1[4].x, q1[4].y, q1[5].x, q1[5].y);
    F[13] = make_float4(q1[6].x, q1[6].y, q1[7].x, q1[7].y);
    F[14] = make_float4(o1[0].x, o1[0].y, o1[1].x, o1[1].y);
    F[15] = make_float4(o1[2].x, o1[2].y, o1[3].x, o1[3].y);
    F[16] = make_float4(b0.x, b0.y, b1.x, b1.y);
  }

  float4* base = g_pk + (size_t)b * NSLOT * 64 + l;
  #pragma unroll
  for (int s = 0; s < NSLOT; ++s) base[s * 64] = F[s];
}

// ---------------- column propagation ----------------
// ONE wave (64 threads) per column; lane l owns rows 8l..8l+7 in registers.
// No LDS, no barriers, no divergence. 4 shuffles per odd layer. All
// coefficient buffers are NAMED registers (identifier-pasted macros) — no
// arrays, no scratch demotion (verify via VGPR_Count ~150-190, not ~40).

__device__ __forceinline__ void cmul(float2& v, float ar, float ai) {
  float xr = ar * v.x - ai * v.y;
  float xi = ar * v.y + ai * v.x;
  v.x = xr; v.y = xi;
}
__device__ __forceinline__ void mmix(float2& top, float2& bot, float t, float r) {
  float a = t * top.x - r * bot.y;
  float b = t * top.y + r * bot.x;
  float c = t * bot.x - r * top.y;
  float d = t * bot.y + r * top.x;
  top.x = a; top.y = b; bot.x = c; bot.y = d;
}

#define PKDECL(V) float4 V##s0,V##s1,V##s2,V##s3,V##s4,V##s5,V##s6,V##s7, \
                         V##s8,V##s9,V##s10,V##s11,V##s12,V##s13,V##s14, \
                         V##s15,V##s16

#define PKLOAD(V, BASE) do { const float4* _b = (BASE); \
  V##s0  = _b[0];      V##s1  = _b[64];     V##s2  = _b[2*64];  V##s3  = _b[3*64]; \
  V##s4  = _b[4*64];   V##s5  = _b[5*64];   V##s6  = _b[6*64];  V##s7  = _b[7*64]; \
  V##s8  = _b[8*64];   V##s9  = _b[9*64];   V##s10 = _b[10*64]; V##s11 = _b[11*64]; \
  V##s12 = _b[12*64];  V##s13 = _b[13*64];  V##s14 = _b[14*64]; V##s15 = _b[15*64]; \
  V##s16 = _b[16*64]; } while (0)

// odd layer: 3 internal pairs + unguarded boundary pairs via lane+-1 shuffles
#define ODDL(cA, cB2, cbx, cby) do { \
  float nbx = __shfl_down(v[0].x, 1); float nby = __shfl_down(v[0].y, 1); \
  float ptx = __shfl_up(v[7].x, 1);   float pty = __shfl_up(v[7].y, 1);   \
  mmix(v[1], v[2], (cA).x, (cA).y); \
  mmix(v[3], v[4], (cA).z, (cA).w); \
  mmix(v[5], v[6], (cB2).x, (cB2).y); \
  { float xr = (cB2).z*v[7].x - (cB2).w*nby; \
    float xi = (cB2).z*v[7].y + (cB2).w*nbx; \
    v[7].x = xr; v[7].y = xi; } \
  { float xr = (cbx)*v[0].x - (cby)*pty; \
    float xi = (cbx)*v[0].y + (cby)*ptx; \
    v[0].x = xr; v[0].y = xi; } \
} while (0)

#define STEP(V) do { \
  mmix(v[0],v[1], V##s0.x,V##s0.y);  mmix(v[2],v[3], V##s0.z,V##s0.w); \
  mmix(v[4],v[5], V##s1.x,V##s1.y);  mmix(v[6],v[7], V##s1.z,V##s1.w); \
  cmul(v[0], V##s2.x,V##s2.y);  cmul(v[1], V##s2.z,V##s2.w); \
  cmul(v[2], V##s3.x,V##s3.y);  cmul(v[3], V##s3.z,V##s3.w); \
  cmul(v[4], V##s4.x,V##s4.y);  cmul(v[5], V##s4.z,V##s4.w); \
  cmul(v[6], V##s5.x,V##s5.y);  cmul(v[7], V##s5.z,V##s5.w); \
  mmix(v[0],v[1], V##s6.x,V##s6.y);  mmix(v[2],v[3], V##s6.z,V##s6.w); \
  mmix(v[4],v[5], V##s7.x,V##s7.y);  mmix(v[6],v[7], V##s7.z,V##s7.w); \
  ODDL(V##s8, V##s9, V##s16.x, V##s16.y); \
  cmul(v[0], V##s10.x,V##s10.y); cmul(v[1], V##s10.z,V##s10.w); \
  cmul(v[2], V##s11.x,V##s11.y); cmul(v[3], V##s11.z,V##s11.w); \
  cmul(v[4], V##s12.x,V##s12.y); cmul(v[5], V##s12.z,V##s12.w); \
  cmul(v[6], V##s13.x,V##s13.y); cmul(v[7], V##s13.z,V##s13.w); \
  ODDL(V##s14, V##s15, V##s16.z, V##s16.w); \
} while (0)

__global__ __launch_bounds__(64, 1) void prop_kernel(float* __restrict__ out,
                                                     int write_complex) {
  const int l   = threadIdx.x;
  const int col = blockIdx.x;
  const int r0  = 8 * l;

  float2 v[8];
  #pragma unroll
  for (int k = 0; k < 8; ++k)
    v[k] = (col == r0 + k) ? make_float2(1.0f, 0.0f) : make_float2(0.0f, 0.0f);

  // Pin
  {
    const float4* gio4 = (const float4*)g_io + 4 * l;
    float4 A0 = gio4[0], A1 = gio4[1], A2 = gio4[2], A3 = gio4[3];
    cmul(v[0], A0.x, A0.y); cmul(v[1], A0.z, A0.w);
    cmul(v[2], A1.x, A1.y); cmul(v[3], A1.z, A1.w);
    cmul(v[4], A2.x, A2.y); cmul(v[5], A2.z, A2.w);
    cmul(v[6], A3.x, A3.y); cmul(v[7], A3.z, A3.w);
  }

  const float4* P = g_pk + l;        // element (step,slot): P[(step*NSLOT+slot)*64]
  PKDECL(A);
  PKDECL(B);
  PKLOAD(A, P);                      // step 0
  PKLOAD(B, P + NSLOT * 64);         // step 1

  #pragma unroll 1
  for (int i = 0; i < NSTEPS; i += 2) {
    STEP(A);                                       // consume step i
    PKLOAD(A, P + (size_t)(i + 2) * NSLOT * 64);   // prefetch i+2 (flies under STEP(B))
    STEP(B);                                       // consume step i+1
    PKLOAD(B, P + (size_t)(i + 3) * NSLOT * 64);   // prefetch i+3 (flies under STEP(A))
  }

  // Pout
  {
    const float4* gio4 = (const float4*)g_io + 256 + 4 * l;
    float4 A0 = gio4[0], A1 = gio4[1], A2 = gio4[2], A3 = gio4[3];
    cmul(v[0], A0.x, A0.y); cmul(v[1], A0.z, A0.w);
    cmul(v[2], A1.x, A1.y); cmul(v[3], A1.z, A1.w);
    cmul(v[4], A2.x, A2.y); cmul(v[5], A2.z, A2.w);
    cmul(v[6], A3.x, A3.y); cmul(v[7], A3.z, A3.w);
  }

  if (write_complex) {
    float2* o = (float2*)out;
    #pragma unroll
    for (int k = 0; k < 8; ++k)
      o[(r0 + k) * NROWS + col] = v[k];
  } else {
    // d_out = 262144 floats: real part of the complex64 matrix
    #pragma unroll
    for (int k = 0; k < 8; ++k)
      out[(r0 + k) * NROWS + col] = v[k].x;
  }
}

// ---------------- launch ----------------

extern "C" void kernel_launch(void* const* d_in, const int* in_sizes, int n_in,
                              void* d_out, int out_size, void* d_ws, size_t ws_size,
                              hipStream_t stream) {
  const float* thf  = (const float*)d_in[0];  // thetas_full     (512,512)
  const float* thio = (const float*)d_in[1];  // thetas_inout    (2,512)
  const float* lpf  = (const float*)d_in[2];  // pc_losses_full  (512,512)
  const float* lpio = (const float*)d_in[3];  // pc_losses_inout (2,512)
  const float* le   = (const float*)d_in[4];  // mmi_losses_even (512,256)
  const float* lo   = (const float*)d_in[5];  // mmi_losses_odd  (512,255)
  const float* ie   = (const float*)d_in[6];  // mmi_imb_even    (512,256)
  const float* io2  = (const float*)d_in[7];  // mmi_imb_odd     (512,255)

  const int write_complex = (out_size >= 2 * NROWS * NROWS) ? 1 : 0;

  precomp_kernel<<<PKSTEPS + 8, 64, 0, stream>>>(
      thf, thio, lpf, lpio, le, lo, ie, io2);
  prop_kernel<<<NROWS, 64, 0, stream>>>((float*)d_out, write_complex);
}

// Round 15
// 222.831 us; speedup vs baseline: 2.6071x; 2.6071x over previous
//
#include <hip/hip_runtime.h>
#include <math.h>
#include <stdint.h>

#define NROWS   512
#define NSTEPS  256
#define PKSTEPS (NSTEPS + 4)   // +4 pad steps: loaded by the 4-deep pipeline, never consumed
#define SLOTB   4096u          // slot stride: 256 float4 * 16B
#define STEPB   20480u         // step stride: 5 slots * 4096B

// Packet stream: [step][slot 0..4][tid 0..255] float4, slot-major (16 lines
// per wave-load -> minimal L2 requests).
//  slot0 = (E0.t, E0.r, E1.t, E1.r)           even-layer coeffs, pair 64w+l
//  slot1 = (P0[R0].re, .im, P0[R0+1].re, .im) phase layer 2i
//  slot2 = (O0 cT.t, cT.r, cB.t, cB.r)        odd layer 2i (cB baked in)
//  slot3 = P1 rows                            phase layer 2i+1
//  slot4 = O1 cT/cB                           odd layer 2i+1
__device__ float4 g_pk[PKSTEPS * 5 * 256];
__device__ float2 g_io[1024];   // [0,512) Pin, [512,1024) Pout

// ---------------- coefficient precompute ----------------

__device__ __forceinline__ float2 pc_coef(float th, float loss) {
  float a = sqrtf(1.0f - loss);
  float s, c;
  sincosf(th, &s, &c);
  return make_float2(a * c, a * s);
}
__device__ __forceinline__ float2 mmi_coef(float loss, float imb) {
  float a = sqrtf(1.0f - loss);
  return make_float2(a * sqrtf(0.5f + imb), a * sqrtf(0.5f - imb));
}

__global__ void precomp_kernel(const float* __restrict__ thf,
                               const float* __restrict__ thio,
                               const float* __restrict__ lpf,
                               const float* __restrict__ lpio,
                               const float* __restrict__ le,
                               const float* __restrict__ lo,
                               const float* __restrict__ ie,
                               const float* __restrict__ io2) {
  const int b   = blockIdx.x;
  const int tid = threadIdx.x;
  if (b >= NSTEPS) {
    int j = (b - NSTEPS) * 256 + tid;   // j in [0,512)
    g_io[j]       = pc_coef(thio[j],       lpio[j]);        // Pin
    g_io[j + 512] = pc_coef(thio[j + 512], lpio[j + 512]);  // Pout
    return;
  }
  const int i  = b;
  const int w  = tid >> 6, l = tid & 63;
  const int R0 = 128 * w + 2 * l;
  const int p  = 64 * w + l;
  const int L0 = 2 * i, L1 = 2 * i + 1;

  float2 e0  = mmi_coef(le[L0 * 256 + p], ie[L0 * 256 + p]);
  float2 e1  = mmi_coef(le[L1 * 256 + p], ie[L1 * 256 + p]);
  float2 p0a = pc_coef(thf[L0 * 512 + R0],     lpf[L0 * 512 + R0]);
  float2 p0b = pc_coef(thf[L0 * 512 + R0 + 1], lpf[L0 * 512 + R0 + 1]);
  float2 p1a = pc_coef(thf[L1 * 512 + R0],     lpf[L1 * 512 + R0]);
  float2 p1b = pc_coef(thf[L1 * 512 + R0 + 1], lpf[L1 * 512 + R0 + 1]);
  float2 one = make_float2(1.0f, 0.0f);
  float2 o0T = (p <= 254) ? mmi_coef(lo[L0 * 255 + p],     io2[L0 * 255 + p])     : one;
  float2 o0B = (p >= 1)   ? mmi_coef(lo[L0 * 255 + p - 1], io2[L0 * 255 + p - 1]) : one;
  float2 o1T = (p <= 254) ? mmi_coef(lo[L1 * 255 + p],     io2[L1 * 255 + p])     : one;
  float2 o1B = (p >= 1)   ? mmi_coef(lo[L1 * 255 + p - 1], io2[L1 * 255 + p - 1]) : one;

  float4* base = g_pk + (i * 5) * 256 + tid;
  base[0]        = make_float4(e0.x,  e0.y,  e1.x,  e1.y);
  base[256]      = make_float4(p0a.x, p0a.y, p0b.x, p0b.y);
  base[2 * 256]  = make_float4(o0T.x, o0T.y, o0B.x, o0B.y);
  base[3 * 256]  = make_float4(p1a.x, p1a.y, p1b.x, p1b.y);
  base[4 * 256]  = make_float4(o1T.x, o1T.y, o1B.x, o1B.y);
}

// ---------------- column propagation ----------------
// Block = 256 threads = 4 waves = one column PAIR (R12 structure, proven).
// The coefficient pipeline is PINNED with inline-asm global_load_dwordx4 +
// counted s_waitcnt vmcnt(15): 4 step-buffers (A..D) rotate, 20 loads in
// flight, load->use distance = 3 steps. The compiler cannot rematerialize
// or sink volatile asm loads (R7/R10/R14 all had their source-level prefetch
// silently folded into demand loads -- VGPR_Count 48/40/36 proved it).

typedef float f4 __attribute__((ext_vector_type(4)));

__device__ __forceinline__ void barrier_lgkm() {
  asm volatile("s_waitcnt lgkmcnt(0)\n\ts_barrier" ::: "memory");
  __builtin_amdgcn_sched_barrier(0);
}

__device__ __forceinline__ void cmul(float2& v, float ar, float ai) {
  float xr = ar * v.x - ai * v.y;
  float xi = ar * v.y + ai * v.x;
  v.x = xr; v.y = xi;
}
__device__ __forceinline__ void mmix(float2& top, float2& bot, float t, float r) {
  float a = t * top.x - r * bot.y;
  float b = t * top.y + r * bot.x;
  float c = t * bot.x - r * top.y;
  float d = t * bot.y + r * top.x;
  top.x = a; top.y = b; bot.x = c; bot.y = d;
}
// v' = t*v + i r*o
__device__ __forceinline__ void upd(float2& v, float t, float r, float2 o) {
  float xr = t * v.x - r * o.y;
  float xi = t * v.y + r * o.x;
  v.x = xr; v.y = xi;
}

#define DECLB(V) f4 V##s0, V##s1, V##s2, V##s3, V##s4

// Issue the 5 slot loads for the next step owned by buffer V, then advance
// the per-slot voffsets by one step. Volatile asm: placement is pinned.
#define ISSUE(V) do { \
  asm volatile("global_load_dwordx4 %0, %1, %2" : "=v"(V##s0) : "v"(vo0), "s"(pkb)); \
  asm volatile("global_load_dwordx4 %0, %1, %2" : "=v"(V##s1) : "v"(vo1), "s"(pkb)); \
  asm volatile("global_load_dwordx4 %0, %1, %2" : "=v"(V##s2) : "v"(vo2), "s"(pkb)); \
  asm volatile("global_load_dwordx4 %0, %1, %2" : "=v"(V##s3) : "v"(vo3), "s"(pkb)); \
  asm volatile("global_load_dwordx4 %0, %1, %2" : "=v"(V##s4) : "v"(vo4), "s"(pkb)); \
  vo0 += STEPB; vo1 += STEPB; vo2 += STEPB; vo3 += STEPB; vo4 += STEPB; \
} while (0)

// Wait until <=15 loads outstanding (i.e. the oldest buffer's 5 landed).
// sched_barrier stops the compiler hoisting consumers above it (rule #18).
#define WAITP() do { \
  asm volatile("s_waitcnt vmcnt(15)"); \
  __builtin_amdgcn_sched_barrier(0); \
} while (0)

__global__ __launch_bounds__(256, 1) void prop_kernel(float* __restrict__ out,
                                                      int write_complex) {
  __shared__ float2 sUp[2][2][4];  // [col][sid][wave]: old row 128w+127
  __shared__ float2 sDn[2][2][4];  // [col][sid][wave]: old row 128w
  const int tid = threadIdx.x;
  const int l = tid & 63, w = tid >> 6;
  const int R0 = 128 * w + 2 * l;
  const int colbase = blockIdx.x * 2;

  float2 v[2][2];  // [col][row-in-lane], constant indices only
  #pragma unroll
  for (int c = 0; c < 2; ++c)
    #pragma unroll
    for (int k = 0; k < 2; ++k)
      v[c][k] = (colbase + c == R0 + k) ? make_float2(1.0f, 0.0f)
                                        : make_float2(0.0f, 0.0f);

  auto odd = [&](f4 c, int sid) {
    // old neighbor state, gathered before any update
    float2 nb0, nb1, pt0, pt1;
    nb0.x = __shfl_down(v[0][0].x, 1); nb0.y = __shfl_down(v[0][0].y, 1);
    nb1.x = __shfl_down(v[1][0].x, 1); nb1.y = __shfl_down(v[1][0].y, 1);
    pt0.x = __shfl_up(v[0][1].x, 1);   pt0.y = __shfl_up(v[0][1].y, 1);
    pt1.x = __shfl_up(v[1][1].x, 1);   pt1.y = __shfl_up(v[1][1].y, 1);
    if (l == 0)  { sDn[0][sid][w] = v[0][0]; sDn[1][sid][w] = v[1][0]; }
    if (l == 63) { sUp[0][sid][w] = v[0][1]; sUp[1][sid][w] = v[1][1]; }
    barrier_lgkm();   // DS-only drain; pinned global loads stay in flight
    if (l == 63 && w < 3) { nb0 = sDn[0][sid][w + 1]; nb1 = sDn[1][sid][w + 1]; }
    if (l == 0 && w > 0)  { pt0 = sUp[0][sid][w - 1]; pt1 = sUp[1][sid][w - 1]; }
    if (!(w == 3 && l == 63)) {          // row 511 passes through
      upd(v[0][1], c[0], c[1], nb0);
      upd(v[1][1], c[0], c[1], nb1);
    }
    if (!(w == 0 && l == 0)) {           // row 0 passes through
      upd(v[0][0], c[2], c[3], pt0);
      upd(v[1][0], c[2], c[3], pt1);
    }
  };

  auto step = [&](f4 q0, f4 q1, f4 q2, f4 q3, f4 q4) {
    mmix(v[0][0], v[0][1], q0[0], q0[1]);            // E(2i)
    mmix(v[1][0], v[1][1], q0[0], q0[1]);
    cmul(v[0][0], q1[0], q1[1]); cmul(v[1][0], q1[0], q1[1]);   // P(2i)
    cmul(v[0][1], q1[2], q1[3]); cmul(v[1][1], q1[2], q1[3]);
    mmix(v[0][0], v[0][1], q0[2], q0[3]);            // E(2i+1)
    mmix(v[1][0], v[1][1], q0[2], q0[3]);
    odd(q2, 0);                                      // O(2i)
    cmul(v[0][0], q3[0], q3[1]); cmul(v[1][0], q3[0], q3[1]);   // P(2i+1)
    cmul(v[0][1], q3[2], q3[3]); cmul(v[1][1], q3[2], q3[3]);
    odd(q4, 1);                                      // O(2i+1)
  };

  // Pin
  {
    float4 a = *(const float4*)(g_io + R0);
    cmul(v[0][0], a.x, a.y); cmul(v[1][0], a.x, a.y);
    cmul(v[0][1], a.z, a.w); cmul(v[1][1], a.z, a.w);
  }

  const uintptr_t pkb = (uintptr_t)(const void*)g_pk;
  uint32_t vo0 = (uint32_t)tid * 16u;
  uint32_t vo1 = vo0 + SLOTB, vo2 = vo0 + 2u * SLOTB,
           vo3 = vo0 + 3u * SLOTB, vo4 = vo0 + 4u * SLOTB;

  DECLB(A); DECLB(B); DECLB(C); DECLB(D);
  ISSUE(A);   // step 0   ( 5 outstanding)
  ISSUE(B);   // step 1   (10)
  ISSUE(C);   // step 2   (15)
  ISSUE(D);   // step 3   (20)

  #pragma unroll 1
  for (int i = 0; i < NSTEPS; i += 4) {
    WAITP(); step(As0, As1, As2, As3, As4); ISSUE(A);   // consume i,   load i+4
    WAITP(); step(Bs0, Bs1, Bs2, Bs3, Bs4); ISSUE(B);   // consume i+1, load i+5
    WAITP(); step(Cs0, Cs1, Cs2, Cs3, Cs4); ISSUE(C);   // consume i+2, load i+6
    WAITP(); step(Ds0, Ds1, Ds2, Ds3, Ds4); ISSUE(D);   // consume i+3, load i+7
  }
  // final ISSUEs read pad steps 256..259 (in-bounds, never consumed)

  // Pout
  {
    float4 a = *(const float4*)(g_io + 512 + R0);
    cmul(v[0][0], a.x, a.y); cmul(v[1][0], a.x, a.y);
    cmul(v[0][1], a.z, a.w); cmul(v[1][1], a.z, a.w);
  }

  if (write_complex) {
    float2* o = (float2*)out;
    #pragma unroll
    for (int c = 0; c < 2; ++c) {
      o[(R0 + 0) * NROWS + colbase + c] = v[c][0];
      o[(R0 + 1) * NROWS + colbase + c] = v[c][1];
    }
  } else {
    // d_out = 262144 floats: real part of the complex64 matrix
    #pragma unroll
    for (int c = 0; c < 2; ++c) {
      out[(R0 + 0) * NROWS + colbase + c] = v[c][0].x;
      out[(R0 + 1) * NROWS + colbase + c] = v[c][1].x;
    }
  }
}

// ---------------- launch ----------------

extern "C" void kernel_launch(void* const* d_in, const int* in_sizes, int n_in,
                              void* d_out, int out_size, void* d_ws, size_t ws_size,
                              hipStream_t stream) {
  const float* thf  = (const float*)d_in[0];  // thetas_full     (512,512)
  const float* thio = (const float*)d_in[1];  // thetas_inout    (2,512)
  const float* lpf  = (const float*)d_in[2];  // pc_losses_full  (512,512)
  const float* lpio = (const float*)d_in[3];  // pc_losses_inout (2,512)
  const float* le   = (const float*)d_in[4];  // mmi_losses_even (512,256)
  const float* lo   = (const float*)d_in[5];  // mmi_losses_odd  (512,255)
  const float* ie   = (const float*)d_in[6];  // mmi_imb_even    (512,256)
  const float* io2  = (const float*)d_in[7];  // mmi_imb_odd     (512,255)

  const int write_complex = (out_size >= 2 * NROWS * NROWS) ? 1 : 0;

  precomp_kernel<<<NSTEPS + 2, 256, 0, stream>>>(
      thf, thio, lpf, lpio, le, lo, ie, io2);
  prop_kernel<<<NROWS / 2, 256, 0, stream>>>((float*)d_out, write_complex);
}